// Round 2
// baseline (537.395 us; speedup 1.0000x reference)
//
#include <hip/hip_runtime.h>
#include <cstdint>
#include <cstddef>

typedef _Float16 f16;
typedef _Float16 half8 __attribute__((ext_vector_type(8)));
typedef float floatx4 __attribute__((ext_vector_type(4)));
typedef unsigned short ushort8 __attribute__((ext_vector_type(8)));

// async global->LDS, 16B per lane. LDS dest = wave-uniform base + lane*16.
__device__ __forceinline__ void gload_lds16(const void* g, void* l) {
    __builtin_amdgcn_global_load_lds(
        (const __attribute__((address_space(1))) void*)g,
        (__attribute__((address_space(3))) void*)l,
        16, 0, 0);
}

// f32 -> bf16 with round-to-nearest-even (bit trick; e>=0, finite here)
__device__ __forceinline__ unsigned short f32_to_bf16(float f) {
    unsigned u = __float_as_uint(f);
    return (unsigned short)((u + 0x7FFFu + ((u >> 16) & 1u)) >> 16);
}
__device__ __forceinline__ float bf16_to_f32(unsigned short h) {
    return __uint_as_float(((unsigned)h) << 16);
}

// ---------------- K0a: f32 -> f16 convert (8 elems/thread) ----------------
__global__ void k_cvt(const float* __restrict__ src, f16* __restrict__ dst, int n8) {
    int i = blockIdx.x * blockDim.x + threadIdx.x;
    if (i >= n8) return;
    const float4* s = (const float4*)src + 2 * (size_t)i;
    float4 a = s[0], b = s[1];
    half8 h;
    h[0] = (f16)a.x; h[1] = (f16)a.y; h[2] = (f16)a.z; h[3] = (f16)a.w;
    h[4] = (f16)b.x; h[5] = (f16)b.y; h[6] = (f16)b.z; h[7] = (f16)b.w;
    ((half8*)dst)[i] = h;
}

// ------- K0b: h_s f32 -> h_s16 (same layout) + h_sT16 (d-major transpose) -------
__global__ void k_hs(const float* __restrict__ hs, f16* __restrict__ hs16, f16* __restrict__ hsT) {
    // grid: B * (S/64) * (D/64) = 4*64*4 = 1024
    int id = blockIdx.x;
    int dt = id & 3;
    int st = (id >> 2) & 63;
    int b  = id >> 8;
    __shared__ f16 tile[64][65];
    int t = threadIdx.x;
    int s0 = st * 64, d0 = dt * 64;
#pragma unroll
    for (int i = 0; i < 16; i++) {
        int e = t + i * 256;
        int r = e >> 6, c = e & 63;
        float v = hs[((size_t)(b * 4096 + s0 + r)) * 256 + d0 + c];
        f16 hv = (f16)v;
        hs16[((size_t)(b * 4096 + s0 + r)) * 256 + d0 + c] = hv;
        tile[r][c] = hv;
    }
    __syncthreads();
#pragma unroll
    for (int i = 0; i < 16; i++) {
        int e = t + i * 256;
        int r = e >> 6, c = e & 63;  // r = d-local, c = s-local
        hsT[((size_t)(b * 256 + d0 + r)) * 4096 + s0 + c] = tile[c][r];
    }
}

// ---- shared 2-phase GEMM tile macros (used by k_energy and k_scores) ----
// Requires locals: Ab, Bsrc (f16*), r0, c0, wave, lane, wr, wc, lm, lq, acc[4][4]
#define GE_STAGE(AS, BS, K0) do { \
    _Pragma("unroll") \
    for (int i_ = 0; i_ < 4; i_++) { \
        int rbase_ = wave * 32 + i_ * 8; \
        int row_ = rbase_ + (lane >> 3); \
        gload_lds16(Ab + (size_t)(r0 + row_) * 256 + (K0) + (lane & 7) * 8, &AS[rbase_ * 64]); \
        gload_lds16(Bsrc + (size_t)(c0 + row_) * 256 + (K0) + (lane & 7) * 8, &BS[rbase_ * 64]); \
    } } while (0)

#define GE_COMPUTE(AS, BS) do { \
    half8 af_[4][2], bf_[4][2]; \
    _Pragma("unroll") \
    for (int mi_ = 0; mi_ < 4; mi_++) \
        _Pragma("unroll") \
        for (int kk_ = 0; kk_ < 2; kk_++) { \
            af_[mi_][kk_] = *(const half8*)&AS[(wr * 64 + mi_ * 16 + lm) * 64 + kk_ * 32 + lq * 8]; \
            bf_[mi_][kk_] = *(const half8*)&BS[(wc * 64 + mi_ * 16 + lm) * 64 + kk_ * 32 + lq * 8]; \
        } \
    _Pragma("unroll") \
    for (int kk_ = 0; kk_ < 2; kk_++) \
        _Pragma("unroll") \
        for (int mi_ = 0; mi_ < 4; mi_++) \
            _Pragma("unroll") \
            for (int ni_ = 0; ni_ < 4; ni_++) \
                acc[mi_][ni_] = __builtin_amdgcn_mfma_f32_16x16x32_f16(af_[mi_][kk_], bf_[ni_][kk_], acc[mi_][ni_], 0, 0, 0); \
    } while (0)

// ---------------- K1: energy = h_s @ W^T  (M=4096 s, N=256 t, K=256) -> f16 ----------------
__global__ __launch_bounds__(256, 2) void k_energy(
    const f16* __restrict__ A,    // h_s16: B*4096*256 (K-contig)
    const f16* __restrict__ Bt,   // W16: 256*256 (N,K) row-major
    f16* __restrict__ C)          // energy16: B*4096*256 (s-major, tgt-contig)
{
    int id = blockIdx.x;
    int tn = id & 1, tm = (id >> 1) & 31, b = id >> 6;
    const f16* Ab = A + (size_t)b * 4096 * 256;
    const f16* Bsrc = Bt;

    __shared__ __align__(16) f16 As0[128 * 64];
    __shared__ __align__(16) f16 Bs0[128 * 64];
    __shared__ __align__(16) f16 As1[128 * 64];
    __shared__ __align__(16) f16 Bs1[128 * 64];

    int tid = threadIdx.x;
    int wave = tid >> 6, lane = tid & 63;
    int wr = wave >> 1, wc = wave & 1;
    int lm = lane & 15, lq = lane >> 4;

    floatx4 acc[4][4] = {};
    int r0 = tm * 128, c0 = tn * 128;

    GE_STAGE(As0, Bs0, 0);
    __syncthreads();
    GE_STAGE(As1, Bs1, 64);
    GE_COMPUTE(As0, Bs0);
    __syncthreads();
    GE_STAGE(As0, Bs0, 128);
    GE_COMPUTE(As1, Bs1);
    __syncthreads();
    GE_STAGE(As1, Bs1, 192);
    GE_COMPUTE(As0, Bs0);
    __syncthreads();
    GE_COMPUTE(As1, Bs1);

#pragma unroll
    for (int mi = 0; mi < 4; mi++)
#pragma unroll
        for (int ni = 0; ni < 4; ni++)
#pragma unroll
            for (int r = 0; r < 4; r++) {
                int row = r0 + wr * 64 + mi * 16 + lq * 4 + r;
                int col = c0 + wc * 64 + ni * 16 + lm;
                C[(size_t)(b * 4096 + row) * 256 + col] = (f16)acc[mi][ni][r];
            }
}

// -------- K2: scores GEMM + mask -> store e=exp(score) as BF16; fused row sumexp atomics --------
__global__ __launch_bounds__(256, 2) void k_scores(
    const f16* __restrict__ A,    // h_t16
    const f16* __restrict__ Bt,   // energy16
    const int* __restrict__ ms,   // B*S
    unsigned short* __restrict__ E, // workspace: B*T*S bf16 (exp(masked score))
    float* __restrict__ rsum)     // B*T, pre-zeroed; Σ_s exp(s) per row (no max shift)
{
    int id = blockIdx.x;
    int tn = id & 31, tm = (id >> 5) & 31, b = id >> 10;
    const f16* Ab = A + (size_t)b * 4096 * 256;
    const f16* Bsrc = Bt + (size_t)b * 4096 * 256;

    __shared__ __align__(16) f16 As0[128 * 64];
    __shared__ __align__(16) f16 Bs0[128 * 64];
    __shared__ __align__(16) f16 As1[128 * 64];
    __shared__ __align__(16) f16 Bs1[128 * 64];

    int tid = threadIdx.x;
    int wave = tid >> 6, lane = tid & 63;
    int wr = wave >> 1, wc = wave & 1;
    int lm = lane & 15, lq = lane >> 4;

    floatx4 acc[4][4] = {};
    int r0 = tm * 128, c0 = tn * 128;

    GE_STAGE(As0, Bs0, 0);
    __syncthreads();
    GE_STAGE(As1, Bs1, 64);
    GE_COMPUTE(As0, Bs0);
    __syncthreads();
    GE_STAGE(As0, Bs0, 128);
    GE_COMPUTE(As1, Bs1);
    __syncthreads();
    GE_STAGE(As1, Bs1, 192);
    GE_COMPUTE(As0, Bs0);
    __syncthreads();
    GE_COMPUTE(As1, Bs1);

    // epilogue: e = mask ? exp(score) : 0; store bf16(e), accumulate f32 row sums
    float rs[4][4] = {};  // [mi][r]
#pragma unroll
    for (int ni = 0; ni < 4; ni++) {
        int col = c0 + wc * 64 + ni * 16 + lm;
        int m = ms[b * 4096 + col];
#pragma unroll
        for (int mi = 0; mi < 4; mi++)
#pragma unroll
            for (int r = 0; r < 4; r++) {
                int row = r0 + wr * 64 + mi * 16 + lq * 4 + r;
                float e = m ? __expf(acc[mi][ni][r]) : 0.0f;
                E[(size_t)(b * 4096 + row) * 4096 + col] = f32_to_bf16(e);
                rs[mi][r] += e;
            }
    }
#pragma unroll
    for (int mi = 0; mi < 4; mi++)
#pragma unroll
        for (int r = 0; r < 4; r++) {
            float v = rs[mi][r];
#pragma unroll
            for (int off = 1; off < 16; off <<= 1)
                v += __shfl_xor(v, off, 16);
            if (lm == 0) {
                int row = r0 + wr * 64 + mi * 16 + lq * 4 + r;
                atomicAdd(&rsum[b * 4096 + row], v);
            }
        }
}

// ------- K4: p = bf16(e)*rinv -> write p f32 to out + context partial GEMM (split-K, f16 partials) -------
// 2-phase: double-buffered LDS (Bs0/Bs1), single barrier per iter, e-loads prefetched 1 iter ahead.
// LDS B-tile uses chunked-XOR layout: chunk g (s/8) at g*4096 + (row ^ 2*(g&3))*16 bytes.
__global__ __launch_bounds__(256, 2) void k_ctx(
    const f16* __restrict__ BtT,          // h_sT16: B*256*4096
    const unsigned short* __restrict__ E, // bf16 e in workspace
    float* __restrict__ P,                // d_out scores region: normalized p (f32)
    const float* __restrict__ rsum,
    f16* __restrict__ part)               // 4 * B*4096*256 f16
{
    int id = blockIdx.x;
    int ks = id & 3, tt = (id >> 2) & 31, b = id >> 7;
    int tid = threadIdx.x;
    int wave = tid >> 6, lane = tid & 63;
    int lm = lane & 15, lq = lane >> 4;

    __shared__ __align__(16) f16 Bs0[8 * 2048];  // 32KB chunked-swizzled, buffer 0
    __shared__ __align__(16) f16 Bs1[8 * 2048];  // buffer 1

    int t0 = tt * 128;
    const f16* Bb = BtT + (size_t)b * 256 * 4096;

    float rinv[2];
    size_t rowbase[2];
#pragma unroll
    for (int mi = 0; mi < 2; mi++) {
        int row = t0 + wave * 32 + mi * 16 + lm;
        int gr = b * 4096 + row;
        rinv[mi] = 1.0f / rsum[gr];
        rowbase[mi] = (size_t)gr * 4096;
    }

    // staging: this wave fills chunks g0,g1; lane's global row is XOR-permuted
    int g0 = wave * 2, g1 = wave * 2 + 1;
    int c0g = 2 * (g0 & 3), c1g = 2 * (g1 & 3);
    const f16* gp0 = Bb + (size_t)(lane ^ c0g) * 4096 + g0 * 8;
    const f16* gp1 = Bb + (size_t)(lane ^ c1g) * 4096 + g1 * 8;
    int lds_off0 = g0 * 2048, lds_off1 = g1 * 2048;

    // read-side lane bases (f16 elements): chunk (kk*4+lq), slot (lm ^ 2lq)
    int rbk[2];
    rbk[0] = (0 * 4 + lq) * 2048 + (lm ^ (2 * lq)) * 8;
    rbk[1] = (1 * 4 + lq) * 2048 + (lm ^ (2 * lq)) * 8;

    floatx4 acc[2][16] = {};
    int sbeg = ks * 1024;

    // ---- prologue: e-loads for it=0, stage tile 0 into Bs0 ----
    ushort8 ev[2][2];
#pragma unroll
    for (int mi = 0; mi < 2; mi++)
#pragma unroll
        for (int kk = 0; kk < 2; kk++)
            ev[mi][kk] = *(const ushort8*)(E + rowbase[mi] + sbeg + kk * 32 + lq * 8);
#pragma unroll
    for (int R = 0; R < 256; R += 64) {
        gload_lds16(gp0 + (size_t)R * 4096 + sbeg, &Bs0[lds_off0 + R * 8]);
        gload_lds16(gp1 + (size_t)R * 4096 + sbeg, &Bs0[lds_off1 + R * 8]);
    }
    __syncthreads();

#define CTX_ITER(IT, BSR, BSW) do { \
    ushort8 evn_[2][2]; \
    if ((IT) < 15) { \
        int s0n_ = sbeg + ((IT) + 1) * 64; \
        _Pragma("unroll") \
        for (int mi = 0; mi < 2; mi++) \
            _Pragma("unroll") \
            for (int kk = 0; kk < 2; kk++) \
                evn_[mi][kk] = *(const ushort8*)(E + rowbase[mi] + s0n_ + kk * 32 + lq * 8); \
        _Pragma("unroll") \
        for (int R = 0; R < 256; R += 64) { \
            gload_lds16(gp0 + (size_t)R * 4096 + s0n_, &BSW[lds_off0 + R * 8]); \
            gload_lds16(gp1 + (size_t)R * 4096 + s0n_, &BSW[lds_off1 + R * 8]); \
        } \
    } \
    int s0c_ = sbeg + (IT) * 64; \
    half8 af_[2][2]; \
    _Pragma("unroll") \
    for (int mi = 0; mi < 2; mi++) \
        _Pragma("unroll") \
        for (int kk = 0; kk < 2; kk++) { \
            half8 h_; \
            _Pragma("unroll") \
            for (int j = 0; j < 8; j++) \
                h_[j] = (f16)(bf16_to_f32(ev[mi][kk][j]) * rinv[mi]); \
            af_[mi][kk] = h_; \
        } \
    _Pragma("unroll") \
    for (int mi = 0; mi < 2; mi++) \
        _Pragma("unroll") \
        for (int kk = 0; kk < 2; kk++) { \
            float* p_ = P + rowbase[mi] + s0c_ + kk * 32 + lq * 8; \
            half8 h_ = af_[mi][kk]; \
            ((float4*)p_)[0] = make_float4((float)h_[0], (float)h_[1], (float)h_[2], (float)h_[3]); \
            ((float4*)p_)[1] = make_float4((float)h_[4], (float)h_[5], (float)h_[6], (float)h_[7]); \
        } \
    _Pragma("unroll") \
    for (int kk = 0; kk < 2; kk++) \
        _Pragma("unroll") \
        for (int ni = 0; ni < 16; ni++) { \
            half8 bf_ = *(const half8*)&BSR[rbk[kk] + ni * 128]; \
            _Pragma("unroll") \
            for (int mi = 0; mi < 2; mi++) \
                acc[mi][ni] = __builtin_amdgcn_mfma_f32_16x16x32_f16(af_[mi][kk], bf_, acc[mi][ni], 0, 0, 0); \
        } \
    __syncthreads(); \
    if ((IT) < 15) { \
        _Pragma("unroll") \
        for (int mi = 0; mi < 2; mi++) \
            _Pragma("unroll") \
            for (int kk = 0; kk < 2; kk++) \
                ev[mi][kk] = evn_[mi][kk]; \
    } } while (0)

    for (int it = 0; it < 16; it += 2) {
        CTX_ITER(it, Bs0, Bs1);
        CTX_ITER(it + 1, Bs1, Bs0);
    }
#undef CTX_ITER

    f16* Pp = part + (size_t)ks * 4194304 + (size_t)b * 1048576;
#pragma unroll
    for (int mi = 0; mi < 2; mi++)
#pragma unroll
        for (int ni = 0; ni < 16; ni++)
#pragma unroll
            for (int r = 0; r < 4; r++) {
                int row = t0 + wave * 32 + mi * 16 + lq * 4 + r;
                int col = ni * 16 + lm;
                Pp[(size_t)row * 256 + col] = (f16)acc[mi][ni][r];
            }
}

// ---------------- K5: reduce 4 split-K f16 partials -> context f32 ----------------
__global__ void k_red(const f16* __restrict__ part, float* __restrict__ out) {
    size_t i = (size_t)blockIdx.x * 256 + threadIdx.x;  // half8 index, N8 = 524288
    const half8* p = (const half8*)part;
    half8 a = p[i];
    half8 b = p[i + 524288];
    half8 c = p[i + 1048576];
    half8 d = p[i + 1572864];
    float4 o0, o1;
    o0.x = (float)a[0] + (float)b[0] + (float)c[0] + (float)d[0];
    o0.y = (float)a[1] + (float)b[1] + (float)c[1] + (float)d[1];
    o0.z = (float)a[2] + (float)b[2] + (float)c[2] + (float)d[2];
    o0.w = (float)a[3] + (float)b[3] + (float)c[3] + (float)d[3];
    o1.x = (float)a[4] + (float)b[4] + (float)c[4] + (float)d[4];
    o1.y = (float)a[5] + (float)b[5] + (float)c[5] + (float)d[5];
    o1.z = (float)a[6] + (float)b[6] + (float)c[6] + (float)d[6];
    o1.w = (float)a[7] + (float)b[7] + (float)c[7] + (float)d[7];
    ((float4*)out)[2 * i] = o0;
    ((float4*)out)[2 * i + 1] = o1;
}

extern "C" void kernel_launch(void* const* d_in, const int* in_sizes, int n_in,
                              void* d_out, int out_size, void* d_ws, size_t ws_size,
                              hipStream_t stream) {
    const float* h_t = (const float*)d_in[0];   // 4*4096*256
    const float* h_s = (const float*)d_in[1];   // 4*4096*256
    const int*   m_s = (const int*)d_in[2];     // 4*4096
    const float* W   = (const float*)d_in[3];   // 256*256

    float* out = (float*)d_out;
    char* ws = (char*)d_ws;
    f16* h_t16 = (f16*)(ws);                      // 8.39 MB
    f16* h_s16 = (f16*)(ws + 8388608);            // 8.39 MB
    f16* h_sT  = (f16*)(ws + 16777216);           // 8.39 MB
    f16* en16  = (f16*)(ws + 25165824);           // 8.39 MB
    f16* W16   = (f16*)(ws + 33554432);           // 128 KB
    float* rsum = (float*)(ws + 33685504);        // 64 KB
    unsigned short* e16 = (unsigned short*)(ws + 33751040);  // 134.2 MB bf16 e
    f16* part = (f16*)(ws + 167968768);           // 33.6 MB f16 partials

    float* ctx = out;              // 4*4096*256 = 4194304
    float* sc  = out + 4194304;    // 4*4096*4096

    hipMemsetAsync(rsum, 0, 16384 * sizeof(float), stream);
    k_cvt<<<2048, 256, 0, stream>>>(h_t, h_t16, 524288);
    k_cvt<<<32, 256, 0, stream>>>(W, W16, 8192);
    k_hs<<<1024, 256, 0, stream>>>(h_s, h_s16, h_sT);
    k_energy<<<256, 256, 0, stream>>>(h_s16, W16, en16);
    k_scores<<<4096, 256, 0, stream>>>(h_t16, en16, m_s, e16, rsum);
    k_ctx<<<512, 256, 0, stream>>>(h_sT, e16, sc, rsum, part);
    k_red<<<2048, 256, 0, stream>>>(part, ctx);
}

// Round 3
// 490.669 us; speedup vs baseline: 1.0952x; 1.0952x over previous
//
#include <hip/hip_runtime.h>
#include <cstdint>
#include <cstddef>

typedef _Float16 f16;
typedef _Float16 half8 __attribute__((ext_vector_type(8)));
typedef float floatx4 __attribute__((ext_vector_type(4)));
typedef unsigned short ushort8 __attribute__((ext_vector_type(8)));

// async global->LDS, 16B per lane. LDS dest = wave-uniform base + lane*16.
__device__ __forceinline__ void gload_lds16(const void* g, void* l) {
    __builtin_amdgcn_global_load_lds(
        (const __attribute__((address_space(1))) void*)g,
        (__attribute__((address_space(3))) void*)l,
        16, 0, 0);
}

// f32 -> bf16 with round-to-nearest-even (bit trick; e>=0, finite here)
__device__ __forceinline__ unsigned short f32_to_bf16(float f) {
    unsigned u = __float_as_uint(f);
    return (unsigned short)((u + 0x7FFFu + ((u >> 16) & 1u)) >> 16);
}
__device__ __forceinline__ float bf16_to_f32(unsigned short h) {
    return __uint_as_float(((unsigned)h) << 16);
}

// ---------------- K0a: fused f32 -> f16 convert for h_t and W ----------------
__global__ void k_cvt2(const float* __restrict__ srcA, f16* __restrict__ dstA, int n8a,
                       const float* __restrict__ srcB, f16* __restrict__ dstB, int n8b) {
    int i = blockIdx.x * blockDim.x + threadIdx.x;
    const float* src;
    f16* dst;
    int j;
    if (i < n8a) { src = srcA; dst = dstA; j = i; }
    else { j = i - n8a; if (j >= n8b) return; src = srcB; dst = dstB; }
    const float4* s = (const float4*)src + 2 * (size_t)j;
    float4 a = s[0], b = s[1];
    half8 h;
    h[0] = (f16)a.x; h[1] = (f16)a.y; h[2] = (f16)a.z; h[3] = (f16)a.w;
    h[4] = (f16)b.x; h[5] = (f16)b.y; h[6] = (f16)b.z; h[7] = (f16)b.w;
    ((half8*)dst)[j] = h;
}

// ------- K0b: h_s f32 -> h_s16 (same layout) + h_sT16 (d-major transpose) -------
__global__ void k_hs(const float* __restrict__ hs, f16* __restrict__ hs16, f16* __restrict__ hsT) {
    // grid: B * (S/64) * (D/64) = 4*64*4 = 1024
    int id = blockIdx.x;
    int dt = id & 3;
    int st = (id >> 2) & 63;
    int b  = id >> 8;
    __shared__ f16 tile[64][65];
    int t = threadIdx.x;
    int s0 = st * 64, d0 = dt * 64;
#pragma unroll
    for (int i = 0; i < 16; i++) {
        int e = t + i * 256;
        int r = e >> 6, c = e & 63;
        float v = hs[((size_t)(b * 4096 + s0 + r)) * 256 + d0 + c];
        f16 hv = (f16)v;
        hs16[((size_t)(b * 4096 + s0 + r)) * 256 + d0 + c] = hv;
        tile[r][c] = hv;
    }
    __syncthreads();
#pragma unroll
    for (int i = 0; i < 16; i++) {
        int e = t + i * 256;
        int r = e >> 6, c = e & 63;  // r = d-local, c = s-local
        hsT[((size_t)(b * 256 + d0 + r)) * 4096 + s0 + c] = tile[c][r];
    }
}

// ---------------- K1: energy = h_s @ W^T  (M=4096 s, N=256 t, K=256) -> f16 ----------------
__global__ __launch_bounds__(256, 2) void k_energy(
    const f16* __restrict__ A,    // h_s16: B*4096*256 (K-contig)
    const f16* __restrict__ Bt,   // W16: 256*256 (N,K) row-major
    f16* __restrict__ C)          // energy16: B*4096*256 (s-major, tgt-contig)
{
    int id = blockIdx.x;
    int tn = id & 1, tm = (id >> 1) & 31, b = id >> 6;
    const f16* Ab = A + (size_t)b * 4096 * 256;

    __shared__ __align__(16) f16 As[128 * 64];
    __shared__ __align__(16) f16 Bs[128 * 64];

    int tid = threadIdx.x;
    int wave = tid >> 6, lane = tid & 63;
    int wr = wave >> 1, wc = wave & 1;
    int lm = lane & 15, lq = lane >> 4;

    floatx4 acc[4][4] = {};
    int r0 = tm * 128, c0 = tn * 128;

    for (int k0 = 0; k0 < 256; k0 += 64) {
#pragma unroll
        for (int i = 0; i < 4; i++) {
            int rbase = wave * 32 + i * 8;
            int row = rbase + (lane >> 3);
            gload_lds16(Ab + (size_t)(r0 + row) * 256 + k0 + (lane & 7) * 8, &As[rbase * 64]);
            gload_lds16(Bt + (size_t)(c0 + row) * 256 + k0 + (lane & 7) * 8, &Bs[rbase * 64]);
        }
        __syncthreads();
        half8 af[4][2], bf[4][2];
#pragma unroll
        for (int mi = 0; mi < 4; mi++)
#pragma unroll
            for (int kk = 0; kk < 2; kk++) {
                af[mi][kk] = *(const half8*)&As[(wr * 64 + mi * 16 + lm) * 64 + kk * 32 + lq * 8];
                bf[mi][kk] = *(const half8*)&Bs[(wc * 64 + mi * 16 + lm) * 64 + kk * 32 + lq * 8];
            }
#pragma unroll
        for (int kk = 0; kk < 2; kk++)
#pragma unroll
            for (int mi = 0; mi < 4; mi++)
#pragma unroll
                for (int ni = 0; ni < 4; ni++)
                    acc[mi][ni] = __builtin_amdgcn_mfma_f32_16x16x32_f16(af[mi][kk], bf[ni][kk], acc[mi][ni], 0, 0, 0);
        __syncthreads();
    }
#pragma unroll
    for (int mi = 0; mi < 4; mi++)
#pragma unroll
        for (int ni = 0; ni < 4; ni++)
#pragma unroll
            for (int r = 0; r < 4; r++) {
                int row = r0 + wr * 64 + mi * 16 + lq * 4 + r;
                int col = c0 + wc * 64 + ni * 16 + lm;
                C[(size_t)(b * 4096 + row) * 256 + col] = (f16)acc[mi][ni][r];
            }
}

// -------- K2: scores GEMM + mask -> store e=exp(score) as BF16; fused row sumexp atomics --------
// bf16 transport: full f32 exponent range (no max-subtract needed), half the write traffic.
__global__ __launch_bounds__(256, 2) void k_scores(
    const f16* __restrict__ A,    // h_t16
    const f16* __restrict__ Bt,   // energy16
    const int* __restrict__ ms,   // B*S
    unsigned short* __restrict__ E, // workspace: B*T*S bf16 (exp(masked score))
    float* __restrict__ rsum)     // B*T, pre-zeroed; Σ_s exp(s) per row (no max shift)
{
    int id = blockIdx.x;
    int tn = id & 31, tm = (id >> 5) & 31, b = id >> 10;
    const f16* Ab = A + (size_t)b * 4096 * 256;
    const f16* Bb = Bt + (size_t)b * 4096 * 256;

    __shared__ __align__(16) f16 As[128 * 64];
    __shared__ __align__(16) f16 Bs[128 * 64];

    int tid = threadIdx.x;
    int wave = tid >> 6, lane = tid & 63;
    int wr = wave >> 1, wc = wave & 1;
    int lm = lane & 15, lq = lane >> 4;

    floatx4 acc[4][4] = {};
    int r0 = tm * 128, c0 = tn * 128;

    for (int k0 = 0; k0 < 256; k0 += 64) {
#pragma unroll
        for (int i = 0; i < 4; i++) {
            int rbase = wave * 32 + i * 8;
            int row = rbase + (lane >> 3);
            gload_lds16(Ab + (size_t)(r0 + row) * 256 + k0 + (lane & 7) * 8, &As[rbase * 64]);
            gload_lds16(Bb + (size_t)(c0 + row) * 256 + k0 + (lane & 7) * 8, &Bs[rbase * 64]);
        }
        __syncthreads();
        half8 af[4][2], bf[4][2];
#pragma unroll
        for (int mi = 0; mi < 4; mi++)
#pragma unroll
            for (int kk = 0; kk < 2; kk++) {
                af[mi][kk] = *(const half8*)&As[(wr * 64 + mi * 16 + lm) * 64 + kk * 32 + lq * 8];
                bf[mi][kk] = *(const half8*)&Bs[(wc * 64 + mi * 16 + lm) * 64 + kk * 32 + lq * 8];
            }
#pragma unroll
        for (int kk = 0; kk < 2; kk++)
#pragma unroll
            for (int mi = 0; mi < 4; mi++)
#pragma unroll
                for (int ni = 0; ni < 4; ni++)
                    acc[mi][ni] = __builtin_amdgcn_mfma_f32_16x16x32_f16(af[mi][kk], bf[ni][kk], acc[mi][ni], 0, 0, 0);
        __syncthreads();
    }
    // epilogue: e = mask ? exp(score) : 0; store bf16(e), accumulate f32 row sums
    float rs[4][4] = {};  // [mi][r]
#pragma unroll
    for (int ni = 0; ni < 4; ni++) {
        int col = c0 + wc * 64 + ni * 16 + lm;
        int m = ms[b * 4096 + col];
#pragma unroll
        for (int mi = 0; mi < 4; mi++)
#pragma unroll
            for (int r = 0; r < 4; r++) {
                int row = r0 + wr * 64 + mi * 16 + lq * 4 + r;
                float e = m ? __expf(acc[mi][ni][r]) : 0.0f;
                E[(size_t)(b * 4096 + row) * 4096 + col] = f32_to_bf16(e);
                rs[mi][r] += e;
            }
    }
#pragma unroll
    for (int mi = 0; mi < 4; mi++)
#pragma unroll
        for (int r = 0; r < 4; r++) {
            float v = rs[mi][r];
#pragma unroll
            for (int off = 1; off < 16; off <<= 1)
                v += __shfl_xor(v, off, 16);
            if (lm == 0) {
                int row = r0 + wr * 64 + mi * 16 + lq * 4 + r;
                atomicAdd(&rsum[b * 4096 + row], v);
            }
        }
}

// ------- K4: p = bf16(e)*rinv -> write p f32 to out + context partial GEMM (split-K, f16 partials) -------
// Register-neutral 2-phase: double-buffered LDS (Bs0/Bs1), ONE barrier per iter.
// NO e-prefetch (e-loads for current iter only — same live VGPR set as the R1 kernel).
// LDS B-tile uses chunked-XOR layout: chunk g (s/8) at g*4096 + (row ^ 2*(g&3))*16 bytes.
__global__ __launch_bounds__(256, 2) void k_ctx(
    const f16* __restrict__ BtT,          // h_sT16: B*256*4096
    const unsigned short* __restrict__ E, // bf16 e in workspace
    float* __restrict__ P,                // d_out scores region: normalized p (f32)
    const float* __restrict__ rsum,
    f16* __restrict__ part)               // 4 * B*4096*256 f16
{
    int id = blockIdx.x;
    int ks = id & 3, tt = (id >> 2) & 31, b = id >> 7;
    int tid = threadIdx.x;
    int wave = tid >> 6, lane = tid & 63;
    int lm = lane & 15, lq = lane >> 4;

    __shared__ __align__(16) f16 Bs0[8 * 2048];  // 32KB chunked-swizzled, buffer 0
    __shared__ __align__(16) f16 Bs1[8 * 2048];  // buffer 1

    int t0 = tt * 128;
    const f16* Bb = BtT + (size_t)b * 256 * 4096;

    float rinv[2];
    size_t rowbase[2];
#pragma unroll
    for (int mi = 0; mi < 2; mi++) {
        int row = t0 + wave * 32 + mi * 16 + lm;
        int gr = b * 4096 + row;
        rinv[mi] = 1.0f / rsum[gr];
        rowbase[mi] = (size_t)gr * 4096;
    }

    // staging: this wave fills chunks g0,g1; lane's global row is XOR-permuted
    int g0 = wave * 2, g1 = wave * 2 + 1;
    int c0g = 2 * (g0 & 3), c1g = 2 * (g1 & 3);
    const f16* gp0 = Bb + (size_t)(lane ^ c0g) * 4096 + g0 * 8;
    const f16* gp1 = Bb + (size_t)(lane ^ c1g) * 4096 + g1 * 8;
    int lds_off0 = g0 * 2048, lds_off1 = g1 * 2048;

    // read-side lane bases (f16 elements): chunk (kk*4+lq), slot (lm ^ 2lq)
    int rbk[2];
    rbk[0] = (0 * 4 + lq) * 2048 + (lm ^ (2 * lq)) * 8;
    rbk[1] = (1 * 4 + lq) * 2048 + (lm ^ (2 * lq)) * 8;

    floatx4 acc[2][16] = {};
    int sbeg = ks * 1024;

    // ---- prologue: stage tile 0 into Bs0 ----
#pragma unroll
    for (int R = 0; R < 256; R += 64) {
        gload_lds16(gp0 + (size_t)R * 4096 + sbeg, &Bs0[lds_off0 + R * 8]);
        gload_lds16(gp1 + (size_t)R * 4096 + sbeg, &Bs0[lds_off1 + R * 8]);
    }
    __syncthreads();

    // Per iteration: {e-loads(it) first; stage(it+1)->write-buf; convert (waits only e-loads,
    //  counted vmcnt); p-write; 64 MFMA from read-buf; ONE barrier (drains stage(it+1),
    //  which had convert+p-write+MFMA (~700cyc) of cover)}.
#define CTX_ITER(IT, BSR, BSW) do { \
    int s0c_ = sbeg + (IT) * 64; \
    ushort8 ev_[2][2]; \
    _Pragma("unroll") \
    for (int mi = 0; mi < 2; mi++) \
        _Pragma("unroll") \
        for (int kk = 0; kk < 2; kk++) \
            ev_[mi][kk] = *(const ushort8*)(E + rowbase[mi] + s0c_ + kk * 32 + lq * 8); \
    if ((IT) < 15) { \
        int s0n_ = s0c_ + 64; \
        _Pragma("unroll") \
        for (int R = 0; R < 256; R += 64) { \
            gload_lds16(gp0 + (size_t)R * 4096 + s0n_, &BSW[lds_off0 + R * 8]); \
            gload_lds16(gp1 + (size_t)R * 4096 + s0n_, &BSW[lds_off1 + R * 8]); \
        } \
    } \
    half8 af_[2][2]; \
    _Pragma("unroll") \
    for (int mi = 0; mi < 2; mi++) \
        _Pragma("unroll") \
        for (int kk = 0; kk < 2; kk++) { \
            half8 h_; \
            _Pragma("unroll") \
            for (int j = 0; j < 8; j++) \
                h_[j] = (f16)(bf16_to_f32(ev_[mi][kk][j]) * rinv[mi]); \
            af_[mi][kk] = h_; \
        } \
    _Pragma("unroll") \
    for (int mi = 0; mi < 2; mi++) \
        _Pragma("unroll") \
        for (int kk = 0; kk < 2; kk++) { \
            float* p_ = P + rowbase[mi] + s0c_ + kk * 32 + lq * 8; \
            half8 h_ = af_[mi][kk]; \
            ((float4*)p_)[0] = make_float4((float)h_[0], (float)h_[1], (float)h_[2], (float)h_[3]); \
            ((float4*)p_)[1] = make_float4((float)h_[4], (float)h_[5], (float)h_[6], (float)h_[7]); \
        } \
    _Pragma("unroll") \
    for (int kk = 0; kk < 2; kk++) \
        _Pragma("unroll") \
        for (int ni = 0; ni < 16; ni++) { \
            half8 bf_ = *(const half8*)&BSR[rbk[kk] + ni * 128]; \
            _Pragma("unroll") \
            for (int mi = 0; mi < 2; mi++) \
                acc[mi][ni] = __builtin_amdgcn_mfma_f32_16x16x32_f16(af_[mi][kk], bf_, acc[mi][ni], 0, 0, 0); \
        } \
    __syncthreads(); \
    } while (0)

    for (int it = 0; it < 16; it += 2) {
        CTX_ITER(it, Bs0, Bs1);
        CTX_ITER(it + 1, Bs1, Bs0);
    }
#undef CTX_ITER

    f16* Pp = part + (size_t)ks * 4194304 + (size_t)b * 1048576;
#pragma unroll
    for (int mi = 0; mi < 2; mi++)
#pragma unroll
        for (int ni = 0; ni < 16; ni++)
#pragma unroll
            for (int r = 0; r < 4; r++) {
                int row = t0 + wave * 32 + mi * 16 + lq * 4 + r;
                int col = ni * 16 + lm;
                Pp[(size_t)row * 256 + col] = (f16)acc[mi][ni][r];
            }
}

// ---------------- K5: reduce 4 split-K f16 partials -> context f32 ----------------
__global__ void k_red(const f16* __restrict__ part, float* __restrict__ out) {
    size_t i = (size_t)blockIdx.x * 256 + threadIdx.x;  // half8 index, N8 = 524288
    const half8* p = (const half8*)part;
    half8 a = p[i];
    half8 b = p[i + 524288];
    half8 c = p[i + 1048576];
    half8 d = p[i + 1572864];
    float4 o0, o1;
    o0.x = (float)a[0] + (float)b[0] + (float)c[0] + (float)d[0];
    o0.y = (float)a[1] + (float)b[1] + (float)c[1] + (float)d[1];
    o0.z = (float)a[2] + (float)b[2] + (float)c[2] + (float)d[2];
    o0.w = (float)a[3] + (float)b[3] + (float)c[3] + (float)d[3];
    o1.x = (float)a[4] + (float)b[4] + (float)c[4] + (float)d[4];
    o1.y = (float)a[5] + (float)b[5] + (float)c[5] + (float)d[5];
    o1.z = (float)a[6] + (float)b[6] + (float)c[6] + (float)d[6];
    o1.w = (float)a[7] + (float)b[7] + (float)c[7] + (float)d[7];
    ((float4*)out)[2 * i] = o0;
    ((float4*)out)[2 * i + 1] = o1;
}

extern "C" void kernel_launch(void* const* d_in, const int* in_sizes, int n_in,
                              void* d_out, int out_size, void* d_ws, size_t ws_size,
                              hipStream_t stream) {
    const float* h_t = (const float*)d_in[0];   // 4*4096*256
    const float* h_s = (const float*)d_in[1];   // 4*4096*256
    const int*   m_s = (const int*)d_in[2];     // 4*4096
    const float* W   = (const float*)d_in[3];   // 256*256

    float* out = (float*)d_out;
    char* ws = (char*)d_ws;
    f16* h_t16 = (f16*)(ws);                      // 8.39 MB
    f16* h_s16 = (f16*)(ws + 8388608);            // 8.39 MB
    f16* h_sT  = (f16*)(ws + 16777216);           // 8.39 MB
    f16* en16  = (f16*)(ws + 25165824);           // 8.39 MB
    f16* W16   = (f16*)(ws + 33554432);           // 128 KB
    float* rsum = (float*)(ws + 33685504);        // 64 KB
    unsigned short* e16 = (unsigned short*)(ws + 33751040);  // 134.2 MB bf16 e
    f16* part = (f16*)(ws + 167968768);           // 33.6 MB f16 partials

    float* ctx = out;              // 4*4096*256 = 4194304
    float* sc  = out + 4194304;    // 4*4096*4096

    hipMemsetAsync(rsum, 0, 16384 * sizeof(float), stream);
    k_cvt2<<<2080, 256, 0, stream>>>(h_t, h_t16, 524288, W, W16, 8192);
    k_hs<<<1024, 256, 0, stream>>>(h_s, h_s16, h_sT);
    k_energy<<<256, 256, 0, stream>>>(h_s16, W16, en16);
    k_scores<<<4096, 256, 0, stream>>>(h_t16, en16, m_s, e16, rsum);
    k_ctx<<<512, 256, 0, stream>>>(h_sT, e16, sc, rsum, part);
    k_red<<<2048, 256, 0, stream>>>(part, ctx);
}